// Round 2
// baseline (1700.647 us; speedup 1.0000x reference)
//
#include <hip/hip_runtime.h>
#include <hip/hip_bf16.h>

#define NUM_ENT   30000
#define NUM_ATTR  10000
#define HIDDEN    200
#define KPAD      224      // HIDDEN padded to 7*32 for MFMA K-tiles
#define NPAD      30080    // NUM_ENT padded to 235*128
#define N_EDGES   600000
#define BATCH     4096
#define XDIM      401      // 2*HIDDEN + 1
#define RRELU_SLOPE 0.22916666666666666f

using bf16x8 = __attribute__((ext_vector_type(8))) short;
using f32x4  = __attribute__((ext_vector_type(4))) float;
typedef __hip_bfloat16 bf16;

// ---------------------------------------------------------------------------
// Zero agg (30000*200 f32) — no hipMemsetAsync, keep everything as kernels.
// ---------------------------------------------------------------------------
__global__ void k_zero(float4* __restrict__ p, int n4) {
    int i = blockIdx.x * blockDim.x + threadIdx.x;
    int stride = gridDim.x * blockDim.x;
    for (; i < n4; i += stride) p[i] = make_float4(0.f, 0.f, 0.f, 0.f);
}

// ---------------------------------------------------------------------------
// Scatter-add  agg[dst] += h0[src] * w[type]   (only dst < NUM_ENT matters)
// One wave per edge; lanes 0..49 each handle a float4 (4 atomics).
// ---------------------------------------------------------------------------
__global__ void k_scatter(const float* __restrict__ ent, const float* __restrict__ attr,
                          const float* __restrict__ w, const int* __restrict__ esrc,
                          const int* __restrict__ edst, const int* __restrict__ etype,
                          float* __restrict__ agg) {
    int gw   = (blockIdx.x * blockDim.x + threadIdx.x) >> 6;
    int lane = threadIdx.x & 63;
    int nw   = (gridDim.x * blockDim.x) >> 6;
    for (int e = gw; e < N_EDGES; e += nw) {
        int dst = edst[e];
        if (dst >= NUM_ENT) continue;           // h[:NUM_ENT] is all that's consumed
        int src = esrc[e];
        int typ = etype[e];
        if (lane < 50) {
            const float* hrow = (src < NUM_ENT)
                ? ent  + (size_t)src * HIDDEN
                : attr + (size_t)(src - NUM_ENT) * HIDDEN;
            float4 hv = *reinterpret_cast<const float4*>(hrow + lane * 4);
            float4 wv = *reinterpret_cast<const float4*>(w + typ * HIDDEN + lane * 4);
            float* ap = agg + (size_t)dst * HIDDEN + lane * 4;
            atomicAdd(ap + 0, hv.x * wv.x);
            atomicAdd(ap + 1, hv.y * wv.y);
            atomicAdd(ap + 2, hv.z * wv.z);
            atomicAdd(ap + 3, hv.w * wv.w);
        }
    }
}

// ---------------------------------------------------------------------------
// S[n][k] = rrelu(agg[n][k] * norm[n])  as bf16, zero-padded to [NPAD][KPAD].
// ---------------------------------------------------------------------------
__global__ void k_build_S(const float* __restrict__ agg, const float* __restrict__ norm,
                          bf16* __restrict__ S) {
    int n = blockIdx.x;
    int k = threadIdx.x;
    if (k >= KPAD) return;
    float v = 0.f;
    if (n < NUM_ENT && k < HIDDEN) {
        v = agg[(size_t)n * HIDDEN + k] * norm[n];
        v = (v >= 0.f) ? v : RRELU_SLOPE * v;
    }
    S[(size_t)n * KPAD + k] = __float2bfloat16(v);
}

// ---------------------------------------------------------------------------
// Y[m][n] = relu( x[m] . dec_W[n] + dec_b[n] )  as bf16 padded to KPAD.
// x[m] = [tanh(static_emb[ent_idx]), rel_emb[rel_idx], time_emb[traw/24]]
// tanh path recomputed from f32 agg (full precision, independent of S).
// ---------------------------------------------------------------------------
__global__ void k_build_Y(const float* __restrict__ agg, const float* __restrict__ norm,
                          const float* __restrict__ rel_emb, const float* __restrict__ time_emb,
                          const float* __restrict__ dec_W, const float* __restrict__ dec_b,
                          const int* __restrict__ batch, bf16* __restrict__ Y) {
    __shared__ float xs[16][405];               // stride 405: odd vs 32 banks, conflict-free
    int t = threadIdx.x;
    int blk = blockIdx.x;
    for (int idx = t; idx < 16 * XDIM; idx += 256) {
        int r = idx / XDIM, c = idx - r * XDIM;
        int m = blk * 16 + r;
        float v;
        if (c < HIDDEN) {
            int e = batch[m * 4 + 0];
            float h = agg[(size_t)e * HIDDEN + c] * norm[e];
            h = (h >= 0.f) ? h : RRELU_SLOPE * h;
            v = tanhf(h);
        } else if (c < 2 * HIDDEN) {
            int rl = batch[m * 4 + 1];
            v = rel_emb[(size_t)rl * HIDDEN + (c - HIDDEN)];
        } else {
            int traw = batch[m * 4 + 3];
            v = time_emb[traw / 24];
        }
        xs[r][c] = v;
    }
    __syncthreads();
    int r = t & 15;                             // batch row within block
    int g = t >> 4;                             // output-column group
    int m = blk * 16 + r;
    for (int n = g; n < KPAD; n += 16) {
        float acc = 0.f;
        if (n < HIDDEN) {
            acc = dec_b[n];
            const float* wrow = dec_W + (size_t)n * XDIM;
            for (int k = 0; k < XDIM; ++k)
                acc += xs[r][k] * wrow[k];
            acc = fmaxf(acc, 0.f);
        }
        Y[(size_t)m * KPAD + n] = __float2bfloat16(acc);
    }
}

// ---------------------------------------------------------------------------
// out[4096][30000] (f32!) = Y(4096xK) . S^T(Kx30000), bf16 MFMA 16x16x32.
// Block 256 thr = 4 waves (2x2), block tile 128x128, wave tile 64x64 (4x4 frags).
// grid = (NPAD/128, BATCH/128) = (235, 32).
// ---------------------------------------------------------------------------
__global__ __launch_bounds__(256) void k_gemm(const bf16* __restrict__ Yb,
                                              const bf16* __restrict__ Sb,
                                              float* __restrict__ out) {
    int wid  = threadIdx.x >> 6;
    int lane = threadIdx.x & 63;
    int wm = wid >> 1, wn = wid & 1;
    int row0 = blockIdx.y * 128 + wm * 64;
    int col0 = blockIdx.x * 128 + wn * 64;
    int rsel = lane & 15;
    int koff = (lane >> 4) * 8;

    const short* Yp = reinterpret_cast<const short*>(Yb);
    const short* Sp = reinterpret_cast<const short*>(Sb);

    f32x4 acc[4][4] = {};
#pragma unroll
    for (int kt = 0; kt < 7; ++kt) {
        int kbase = kt * 32 + koff;
        bf16x8 a[4], b[4];
#pragma unroll
        for (int i = 0; i < 4; ++i)
            a[i] = *reinterpret_cast<const bf16x8*>(Yp + (size_t)(row0 + i * 16 + rsel) * KPAD + kbase);
#pragma unroll
        for (int j = 0; j < 4; ++j)
            b[j] = *reinterpret_cast<const bf16x8*>(Sp + (size_t)(col0 + j * 16 + rsel) * KPAD + kbase);
#pragma unroll
        for (int i = 0; i < 4; ++i)
#pragma unroll
            for (int j = 0; j < 4; ++j)
                acc[i][j] = __builtin_amdgcn_mfma_f32_16x16x32_bf16(a[i], b[j], acc[i][j], 0, 0, 0);
    }

    int crow = (lane >> 4) * 4;     // C/D layout (m89-verified): col=lane&15, row=(lane>>4)*4+r
    int ccol = lane & 15;
#pragma unroll
    for (int i = 0; i < 4; ++i)
#pragma unroll
        for (int j = 0; j < 4; ++j) {
            int col = col0 + j * 16 + ccol;
            if (col >= NUM_ENT) continue;
#pragma unroll
            for (int r = 0; r < 4; ++r) {
                int row = row0 + i * 16 + crow + r;
                out[(size_t)row * NUM_ENT + col] = acc[i][j][r];   // f32 output
            }
        }
}

// ---------------------------------------------------------------------------
extern "C" void kernel_launch(void* const* d_in, const int* in_sizes, int n_in,
                              void* d_out, int out_size, void* d_ws, size_t ws_size,
                              hipStream_t stream) {
    const float* ent_emb  = (const float*)d_in[0];
    const float* attr_emb = (const float*)d_in[1];
    const float* rel_emb  = (const float*)d_in[2];
    const float* time_emb = (const float*)d_in[3];
    const float* rgcn_w   = (const float*)d_in[4];
    const float* dec_W    = (const float*)d_in[5];
    const float* dec_b    = (const float*)d_in[6];
    const float* norm     = (const float*)d_in[7];
    const int*   esrc     = (const int*)d_in[8];
    const int*   edst     = (const int*)d_in[9];
    const int*   etype    = (const int*)d_in[10];
    const int*   batch    = (const int*)d_in[11];

    char* ws = (char*)d_ws;
    float* agg = (float*)ws;                                    // 30000*200*4 = 24,000,000 B
    bf16*  S   = (bf16*)(ws + 24000000);                        // 30080*224*2 = 13,475,840 B
    bf16*  Y   = (bf16*)(ws + 24000000 + 13475840);             //  4096*224*2 =  1,835,008 B

    k_zero<<<2048, 256, 0, stream>>>((float4*)agg, NUM_ENT * HIDDEN / 4);
    k_scatter<<<8192, 256, 0, stream>>>(ent_emb, attr_emb, rgcn_w, esrc, edst, etype, agg);
    k_build_S<<<NPAD, 256, 0, stream>>>(agg, norm, S);
    k_build_Y<<<BATCH / 16, 256, 0, stream>>>(agg, norm, rel_emb, time_emb, dec_W, dec_b, batch, Y);

    dim3 grid(NPAD / 128, BATCH / 128);
    k_gemm<<<grid, 256, 0, stream>>>(Y, S, (float*)d_out);
}

// Round 3
// 657.335 us; speedup vs baseline: 2.5872x; 2.5872x over previous
//
#include <hip/hip_runtime.h>
#include <hip/hip_bf16.h>

#define NUM_ENT   30000
#define NUM_ATTR  10000
#define HIDDEN    200
#define KPAD      224      // HIDDEN padded to 7*32 for MFMA K-tiles
#define NPAD      30080    // NUM_ENT padded to 235*128
#define N_EDGES   600000
#define BATCH     4096
#define XDIM      401      // 2*HIDDEN + 1
#define RRELU_SLOPE 0.22916666666666666f

using bf16x8 = __attribute__((ext_vector_type(8))) short;
using f32x4  = __attribute__((ext_vector_type(4))) float;
typedef __hip_bfloat16 bf16;

// ---------------------------------------------------------------------------
// Zero an int array (histogram counters).
// ---------------------------------------------------------------------------
__global__ void k_zero_i(int* __restrict__ p, int n) {
    int i = blockIdx.x * blockDim.x + threadIdx.x;
    if (i < n) p[i] = 0;
}

// ---------------------------------------------------------------------------
// Histogram of edge destinations (dst < NUM_ENT only).
// ---------------------------------------------------------------------------
__global__ void k_hist(const int* __restrict__ edst, int* __restrict__ counts) {
    int e = blockIdx.x * blockDim.x + threadIdx.x;
    if (e < N_EDGES) {
        int d = edst[e];
        if (d < NUM_ENT) atomicAdd(&counts[d], 1);
    }
}

// ---------------------------------------------------------------------------
// Exclusive prefix sum over 30000 counts -> offsets[0..NUM_ENT], cursor copy.
// Single block, 1024 threads, 30 elements/thread + Hillis-Steele block scan.
// ---------------------------------------------------------------------------
__global__ __launch_bounds__(1024) void k_scan(const int* __restrict__ counts,
                                               int* __restrict__ offsets,
                                               int* __restrict__ cursor) {
    __shared__ int part[1024];
    int t = threadIdx.x;
    const int CH = (NUM_ENT + 1023) / 1024;     // 30
    int base = t * CH;
    int s = 0;
    for (int i = 0; i < CH; ++i) {
        int idx = base + i;
        if (idx < NUM_ENT) s += counts[idx];
    }
    part[t] = s;
    __syncthreads();
    for (int off = 1; off < 1024; off <<= 1) {
        int v = (t >= off) ? part[t - off] : 0;
        __syncthreads();
        part[t] += v;
        __syncthreads();
    }
    int run = (t == 0) ? 0 : part[t - 1];
    for (int i = 0; i < CH; ++i) {
        int idx = base + i;
        if (idx < NUM_ENT) {
            offsets[idx] = run;
            cursor[idx]  = run;
            run += counts[idx];
        }
    }
    if (t == 1023) offsets[NUM_ENT] = part[1023];
}

// ---------------------------------------------------------------------------
// Bucket edge ids by destination node.
// ---------------------------------------------------------------------------
__global__ void k_place(const int* __restrict__ edst, int* __restrict__ cursor,
                        int* __restrict__ sorted) {
    int e = blockIdx.x * blockDim.x + threadIdx.x;
    if (e < N_EDGES) {
        int d = edst[e];
        if (d < NUM_ENT) {
            int p = atomicAdd(&cursor[d], 1);
            sorted[p] = e;
        }
    }
}

// ---------------------------------------------------------------------------
// One wave per node: register-accumulate msg sum over the node's edge bucket,
// write agg (f32) once, and write S row (rrelu * norm -> bf16, padded).
// No atomics. Grid = NPAD waves (rows 30000..30079 are S zero-pad rows).
// ---------------------------------------------------------------------------
__global__ void k_aggregate(const float* __restrict__ ent, const float* __restrict__ attr,
                            const float* __restrict__ w, const int* __restrict__ esrc,
                            const int* __restrict__ etype, const int* __restrict__ offsets,
                            const int* __restrict__ sorted, const float* __restrict__ norm,
                            float* __restrict__ agg, bf16* __restrict__ S) {
    int n    = (blockIdx.x * blockDim.x + threadIdx.x) >> 6;
    int lane = threadIdx.x & 63;
    if (n >= NPAD) return;

    if (n >= NUM_ENT) {                         // S zero-pad rows
        if (lane < KPAD / 4) {
            bf16 z4[4] = {};
            *reinterpret_cast<uint2*>(S + (size_t)n * KPAD + lane * 4) =
                *reinterpret_cast<uint2*>(z4);
        }
        return;
    }

    int beg = offsets[n], end = offsets[n + 1];
    float4 acc = make_float4(0.f, 0.f, 0.f, 0.f);
    for (int e = beg; e < end; ++e) {
        int eid = sorted[e];
        int src = esrc[eid];
        int typ = etype[eid];
        if (lane < 50) {
            const float* hrow = (src < NUM_ENT)
                ? ent  + (size_t)src * HIDDEN
                : attr + (size_t)(src - NUM_ENT) * HIDDEN;
            float4 hv = *reinterpret_cast<const float4*>(hrow + lane * 4);
            float4 wv = *reinterpret_cast<const float4*>(w + typ * HIDDEN + lane * 4);
            acc.x += hv.x * wv.x;
            acc.y += hv.y * wv.y;
            acc.z += hv.z * wv.z;
            acc.w += hv.w * wv.w;
        }
    }

    if (lane < 50) {
        *reinterpret_cast<float4*>(agg + (size_t)n * HIDDEN + lane * 4) = acc;
        float nm = norm[n];
        float v0 = acc.x * nm, v1 = acc.y * nm, v2 = acc.z * nm, v3 = acc.w * nm;
        v0 = (v0 >= 0.f) ? v0 : RRELU_SLOPE * v0;
        v1 = (v1 >= 0.f) ? v1 : RRELU_SLOPE * v1;
        v2 = (v2 >= 0.f) ? v2 : RRELU_SLOPE * v2;
        v3 = (v3 >= 0.f) ? v3 : RRELU_SLOPE * v3;
        bf16 t4[4] = {__float2bfloat16(v0), __float2bfloat16(v1),
                      __float2bfloat16(v2), __float2bfloat16(v3)};
        *reinterpret_cast<uint2*>(S + (size_t)n * KPAD + lane * 4) =
            *reinterpret_cast<uint2*>(t4);
    } else if (lane < KPAD / 4) {               // K-pad 200..223 -> zero
        bf16 z4[4] = {};
        *reinterpret_cast<uint2*>(S + (size_t)n * KPAD + lane * 4) =
            *reinterpret_cast<uint2*>(z4);
    }
}

// ---------------------------------------------------------------------------
// Y[m][n] = relu( x[m] . dec_W[n] + dec_b[n] )  as bf16 padded to KPAD.
// x[m] = [tanh(static_emb[ent_idx]), rel_emb[rel_idx], time_emb[traw/24]]
// ---------------------------------------------------------------------------
__global__ void k_build_Y(const float* __restrict__ agg, const float* __restrict__ norm,
                          const float* __restrict__ rel_emb, const float* __restrict__ time_emb,
                          const float* __restrict__ dec_W, const float* __restrict__ dec_b,
                          const int* __restrict__ batch, bf16* __restrict__ Y) {
    __shared__ float xs[16][405];               // stride 405: odd vs 32 banks, conflict-free
    int t = threadIdx.x;
    int blk = blockIdx.x;
    for (int idx = t; idx < 16 * XDIM; idx += 256) {
        int r = idx / XDIM, c = idx - r * XDIM;
        int m = blk * 16 + r;
        float v;
        if (c < HIDDEN) {
            int e = batch[m * 4 + 0];
            float h = agg[(size_t)e * HIDDEN + c] * norm[e];
            h = (h >= 0.f) ? h : RRELU_SLOPE * h;
            v = tanhf(h);
        } else if (c < 2 * HIDDEN) {
            int rl = batch[m * 4 + 1];
            v = rel_emb[(size_t)rl * HIDDEN + (c - HIDDEN)];
        } else {
            int traw = batch[m * 4 + 3];
            v = time_emb[traw / 24];
        }
        xs[r][c] = v;
    }
    __syncthreads();
    int r = t & 15;                             // batch row within block
    int g = t >> 4;                             // output-column group
    int m = blk * 16 + r;
    for (int n = g; n < KPAD; n += 16) {
        float acc = 0.f;
        if (n < HIDDEN) {
            acc = dec_b[n];
            const float* wrow = dec_W + (size_t)n * XDIM;
            for (int k = 0; k < XDIM; ++k)
                acc += xs[r][k] * wrow[k];
            acc = fmaxf(acc, 0.f);
        }
        Y[(size_t)m * KPAD + n] = __float2bfloat16(acc);
    }
}

// ---------------------------------------------------------------------------
// out[4096][30000] (f32) = Y(4096xK) . S^T(Kx30000), bf16 MFMA 16x16x32.
// Block 256 thr = 4 waves (2x2), block tile 128x128, wave tile 64x64.
// ---------------------------------------------------------------------------
__global__ __launch_bounds__(256) void k_gemm(const bf16* __restrict__ Yb,
                                              const bf16* __restrict__ Sb,
                                              float* __restrict__ out) {
    int wid  = threadIdx.x >> 6;
    int lane = threadIdx.x & 63;
    int wm = wid >> 1, wn = wid & 1;
    int row0 = blockIdx.y * 128 + wm * 64;
    int col0 = blockIdx.x * 128 + wn * 64;
    int rsel = lane & 15;
    int koff = (lane >> 4) * 8;

    const short* Yp = reinterpret_cast<const short*>(Yb);
    const short* Sp = reinterpret_cast<const short*>(Sb);

    f32x4 acc[4][4] = {};
#pragma unroll
    for (int kt = 0; kt < 7; ++kt) {
        int kbase = kt * 32 + koff;
        bf16x8 a[4], b[4];
#pragma unroll
        for (int i = 0; i < 4; ++i)
            a[i] = *reinterpret_cast<const bf16x8*>(Yp + (size_t)(row0 + i * 16 + rsel) * KPAD + kbase);
#pragma unroll
        for (int j = 0; j < 4; ++j)
            b[j] = *reinterpret_cast<const bf16x8*>(Sp + (size_t)(col0 + j * 16 + rsel) * KPAD + kbase);
#pragma unroll
        for (int i = 0; i < 4; ++i)
#pragma unroll
            for (int j = 0; j < 4; ++j)
                acc[i][j] = __builtin_amdgcn_mfma_f32_16x16x32_bf16(a[i], b[j], acc[i][j], 0, 0, 0);
    }

    int crow = (lane >> 4) * 4;     // C/D layout: col=lane&15, row=(lane>>4)*4+r
    int ccol = lane & 15;
#pragma unroll
    for (int i = 0; i < 4; ++i)
#pragma unroll
        for (int j = 0; j < 4; ++j) {
            int col = col0 + j * 16 + ccol;
            if (col >= NUM_ENT) continue;
#pragma unroll
            for (int r = 0; r < 4; ++r) {
                int row = row0 + i * 16 + crow + r;
                out[(size_t)row * NUM_ENT + col] = acc[i][j][r];
            }
        }
}

// ---------------------------------------------------------------------------
extern "C" void kernel_launch(void* const* d_in, const int* in_sizes, int n_in,
                              void* d_out, int out_size, void* d_ws, size_t ws_size,
                              hipStream_t stream) {
    const float* ent_emb  = (const float*)d_in[0];
    const float* attr_emb = (const float*)d_in[1];
    const float* rel_emb  = (const float*)d_in[2];
    const float* time_emb = (const float*)d_in[3];
    const float* rgcn_w   = (const float*)d_in[4];
    const float* dec_W    = (const float*)d_in[5];
    const float* dec_b    = (const float*)d_in[6];
    const float* norm     = (const float*)d_in[7];
    const int*   esrc     = (const int*)d_in[8];
    const int*   edst     = (const int*)d_in[9];
    const int*   etype    = (const int*)d_in[10];
    const int*   batch    = (const int*)d_in[11];

    char* ws = (char*)d_ws;
    float* agg    = (float*)ws;                         // 24,000,000 B
    bf16*  S      = (bf16*)(ws + 24000000);             // 13,475,840 B
    bf16*  Y      = (bf16*)(ws + 37475840);             //  1,835,008 B
    int*   counts = (int*)(ws + 39310848);              //   120,064 B (30001 ints)
    int*   offs   = (int*)(ws + 39430912);              //   120,064 B (30001 ints)
    int*   cursor = (int*)(ws + 39550976);              //   120,064 B (30000 ints)
    int*   sorted = (int*)(ws + 39671040);              // 2,400,000 B (600000 ints)

    k_zero_i<<<(NUM_ENT + 1 + 255) / 256, 256, 0, stream>>>(counts, NUM_ENT + 1);
    k_hist  <<<(N_EDGES + 255) / 256, 256, 0, stream>>>(edst, counts);
    k_scan  <<<1, 1024, 0, stream>>>(counts, offs, cursor);
    k_place <<<(N_EDGES + 255) / 256, 256, 0, stream>>>(edst, cursor, sorted);
    k_aggregate<<<(NPAD + 3) / 4, 256, 0, stream>>>(ent_emb, attr_emb, rgcn_w, esrc, etype,
                                                    offs, sorted, norm, agg, S);
    k_build_Y<<<BATCH / 16, 256, 0, stream>>>(agg, norm, rel_emb, time_emb, dec_W, dec_b, batch, Y);

    dim3 grid(NPAD / 128, BATCH / 128);
    k_gemm<<<grid, 256, 0, stream>>>(Y, S, (float*)d_out);
}